// Round 2
// baseline (429.502 us; speedup 1.0000x reference)
//
#include <hip/hip_runtime.h>

#define N_NODES 100000
#define N_EDGES 1600000
#define LAT 128
#define MAT 8
#define OUTC 3

// ---------------- CSR build ----------------

__global__ void k_count(const int* __restrict__ dst, int* __restrict__ cnt) {
    int e = blockIdx.x * blockDim.x + threadIdx.x;
    if (e < N_EDGES) atomicAdd(&cnt[dst[e]], 1);
}

__global__ void k_dinv(const int* __restrict__ cnt, float* __restrict__ dinv) {
    int i = blockIdx.x * blockDim.x + threadIdx.x;
    if (i < N_NODES) dinv[i] = rsqrtf((float)cnt[i] + 1.0f);  // +1 self-loop
}

// exclusive scan, 1024 elements per block (256 threads x 4)
__global__ __launch_bounds__(256) void k_scan1(const int* __restrict__ cnt,
                                               int* __restrict__ rowptr,
                                               int* __restrict__ blockSums) {
    __shared__ int wsum[4];
    int t = threadIdx.x;
    int lane = t & 63, w = t >> 6;
    int idx = blockIdx.x * 1024 + t * 4;
    int v0 = (idx + 0 < N_NODES) ? cnt[idx + 0] : 0;
    int v1 = (idx + 1 < N_NODES) ? cnt[idx + 1] : 0;
    int v2 = (idx + 2 < N_NODES) ? cnt[idx + 2] : 0;
    int v3 = (idx + 3 < N_NODES) ? cnt[idx + 3] : 0;
    int ts = v0 + v1 + v2 + v3;
    int x = ts;
#pragma unroll
    for (int off = 1; off < 64; off <<= 1) {
        int y = __shfl_up(x, off, 64);
        if (lane >= off) x += y;
    }
    if (lane == 63) wsum[w] = x;
    __syncthreads();
    int wo = 0;
#pragma unroll
    for (int i = 0; i < 4; ++i)
        if (i < w) wo += wsum[i];
    int base = wo + x - ts;  // exclusive prefix for this thread's first element
    if (idx + 0 < N_NODES) rowptr[idx + 0] = base;
    if (idx + 1 < N_NODES) rowptr[idx + 1] = base + v0;
    if (idx + 2 < N_NODES) rowptr[idx + 2] = base + v0 + v1;
    if (idx + 3 < N_NODES) rowptr[idx + 3] = base + v0 + v1 + v2;
    if (t == 255) blockSums[blockIdx.x] = wo + x;  // block total
}

__global__ void k_scan2(int* __restrict__ blockSums, int nb) {
    if (threadIdx.x == 0 && blockIdx.x == 0) {
        int run = 0;
        for (int i = 0; i < nb; ++i) { int v = blockSums[i]; blockSums[i] = run; run += v; }
    }
}

__global__ void k_scan3(int* __restrict__ rowptr, const int* __restrict__ blockSums,
                        int* __restrict__ cursor) {
    int i = blockIdx.x * blockDim.x + threadIdx.x;
    if (i < N_NODES) {
        int r = rowptr[i] + blockSums[i >> 10];
        rowptr[i] = r;
        cursor[i] = r;
    }
    if (i == 0) rowptr[N_NODES] = N_EDGES;
}

__global__ void k_scatter(const int* __restrict__ src, const int* __restrict__ dst,
                          int* __restrict__ cursor, int* __restrict__ colsrc) {
    int e = blockIdx.x * blockDim.x + threadIdx.x;
    if (e < N_EDGES) {
        int d = dst[e];
        int pos = atomicAdd(&cursor[d], 1);
        colsrc[pos] = src[e];
    }
}

// ---------------- GEMM1: g1 = (concat(z, mat) @ W1) * dinv[n] ----------------
// block = 256 threads, 32 nodes/block. thread -> group g = tid>>5 (4 nodes),
// output quad jq = (tid&31)*4. W1 (136x128 = 69.6KB) staged in LDS.
__global__ __launch_bounds__(256) void k_gemm1(const float* __restrict__ z,
                                               const float* __restrict__ mat,
                                               const float* __restrict__ W1,
                                               const float* __restrict__ dinv,
                                               float* __restrict__ g1) {
    __shared__ float w1s[(LAT + MAT) * LAT];
    for (int i = threadIdx.x; i < (LAT + MAT) * LAT; i += 256) w1s[i] = W1[i];
    __syncthreads();
    int g = threadIdx.x >> 5;
    int jq = (threadIdx.x & 31) * 4;
    int n0 = blockIdx.x * 32 + g * 4;
    float acc[4][4] = {{0.f}};
    // z part: k = 0..127
    for (int k4 = 0; k4 < 32; ++k4) {
        float w[4][4];
#pragma unroll
        for (int t = 0; t < 4; ++t)
            *(float4*)&w[t][0] = *(const float4*)&w1s[(k4 * 4 + t) * LAT + jq];
#pragma unroll
        for (int i = 0; i < 4; ++i) {
            float4 xv = *(const float4*)&z[(size_t)(n0 + i) * LAT + k4 * 4];
#pragma unroll
            for (int c = 0; c < 4; ++c)
                acc[i][c] += xv.x * w[0][c] + xv.y * w[1][c] + xv.z * w[2][c] + xv.w * w[3][c];
        }
    }
    // mat part: k = 128..135
#pragma unroll
    for (int h = 0; h < 2; ++h) {
        float w[4][4];
#pragma unroll
        for (int t = 0; t < 4; ++t)
            *(float4*)&w[t][0] = *(const float4*)&w1s[(LAT + h * 4 + t) * LAT + jq];
#pragma unroll
        for (int i = 0; i < 4; ++i) {
            float4 xv = *(const float4*)&mat[(size_t)(n0 + i) * MAT + h * 4];
#pragma unroll
            for (int c = 0; c < 4; ++c)
                acc[i][c] += xv.x * w[0][c] + xv.y * w[1][c] + xv.z * w[2][c] + xv.w * w[3][c];
        }
    }
#pragma unroll
    for (int i = 0; i < 4; ++i) {
        float d = dinv[n0 + i];
        float4 o = make_float4(acc[i][0] * d, acc[i][1] * d, acc[i][2] * d, acc[i][3] * d);
        *(float4*)&g1[(size_t)(n0 + i) * LAT + jq] = o;
    }
}

// ---------------- gather layer1 + fused 128x3 GEMM2 ----------------
// one wave per node; lane holds float2 of the 128-wide row.
// x1 = relu(dinv[n]*(g1[n] + sum g1[src]) + b1); g2[n] = (x1 @ W2) * dinv[n]
__global__ __launch_bounds__(256) void k_gather1(const float* __restrict__ g1,
                                                 const int* __restrict__ colsrc,
                                                 const int* __restrict__ rowptr,
                                                 const float* __restrict__ dinv,
                                                 const float* __restrict__ b1,
                                                 const float* __restrict__ W2,
                                                 float* __restrict__ g2) {
    int n = blockIdx.x * 4 + (threadIdx.x >> 6);
    int lane = threadIdx.x & 63;
    const float2* g1v = (const float2*)g1;
    float2 a = g1v[(size_t)n * 64 + lane];
    float ax = a.x, ay = a.y;
    int e = rowptr[n], eEnd = rowptr[n + 1];
    for (; e + 4 <= eEnd; e += 4) {
        int s0 = colsrc[e], s1 = colsrc[e + 1], s2 = colsrc[e + 2], s3 = colsrc[e + 3];
        float2 v0 = g1v[(size_t)s0 * 64 + lane];
        float2 v1 = g1v[(size_t)s1 * 64 + lane];
        float2 v2 = g1v[(size_t)s2 * 64 + lane];
        float2 v3 = g1v[(size_t)s3 * 64 + lane];
        ax += v0.x + v1.x + v2.x + v3.x;
        ay += v0.y + v1.y + v2.y + v3.y;
    }
    for (; e < eEnd; ++e) {
        int s = colsrc[e];
        float2 v = g1v[(size_t)s * 64 + lane];
        ax += v.x; ay += v.y;
    }
    float d = dinv[n];
    float2 bb = ((const float2*)b1)[lane];
    float x0 = fmaxf(ax * d + bb.x, 0.f);
    float x1 = fmaxf(ay * d + bb.y, 0.f);
    float p0 = x0 * W2[(2 * lane) * OUTC + 0] + x1 * W2[(2 * lane + 1) * OUTC + 0];
    float p1 = x0 * W2[(2 * lane) * OUTC + 1] + x1 * W2[(2 * lane + 1) * OUTC + 1];
    float p2 = x0 * W2[(2 * lane) * OUTC + 2] + x1 * W2[(2 * lane + 1) * OUTC + 2];
#pragma unroll
    for (int off = 32; off > 0; off >>= 1) {
        p0 += __shfl_down(p0, off, 64);
        p1 += __shfl_down(p1, off, 64);
        p2 += __shfl_down(p2, off, 64);
    }
    if (lane == 0) ((float4*)g2)[n] = make_float4(p0 * d, p1 * d, p2 * d, 0.f);
}

// ---------------- gather layer2: out = dinv[n]*(g2[n] + sum g2[src]) + b2 ----------------
__global__ void k_gather2(const float* __restrict__ g2, const int* __restrict__ colsrc,
                          const int* __restrict__ rowptr, const float* __restrict__ dinv,
                          const float* __restrict__ b2, float* __restrict__ out) {
    int n = blockIdx.x * blockDim.x + threadIdx.x;
    if (n >= N_NODES) return;
    const float4* gv = (const float4*)g2;
    float4 a = gv[n];
    float s0 = a.x, s1 = a.y, s2 = a.z;
    int eEnd = rowptr[n + 1];
    for (int e = rowptr[n]; e < eEnd; ++e) {
        float4 v = gv[colsrc[e]];
        s0 += v.x; s1 += v.y; s2 += v.z;
    }
    float d = dinv[n];
    out[(size_t)n * 3 + 0] = s0 * d + b2[0];
    out[(size_t)n * 3 + 1] = s1 * d + b2[1];
    out[(size_t)n * 3 + 2] = s2 * d + b2[2];
}

// ---------------- launch ----------------

extern "C" void kernel_launch(void* const* d_in, const int* in_sizes, int n_in,
                              void* d_out, int out_size, void* d_ws, size_t ws_size,
                              hipStream_t stream) {
    const float* z   = (const float*)d_in[0];
    const int*   ei  = (const int*)d_in[1];   // [2, E] int32
    const float* mat = (const float*)d_in[2];
    const float* W1  = (const float*)d_in[3];
    const float* b1  = (const float*)d_in[4];
    const float* W2  = (const float*)d_in[5];
    const float* b2  = (const float*)d_in[6];
    float* out = (float*)d_out;

    const int* srcA = ei;             // row 0 = message source
    const int* dstA = ei + N_EDGES;   // row 1 = message target

    char* ws = (char*)d_ws;
    auto alloc = [&](size_t bytes) {
        char* p = ws;
        ws += (bytes + 255) & ~(size_t)255;
        return p;
    };
    int*   cnt       = (int*)alloc((size_t)N_NODES * 4);
    int*   rowptr    = (int*)alloc((size_t)(N_NODES + 1) * 4);
    int*   cursor    = (int*)alloc((size_t)N_NODES * 4);
    float* dinv      = (float*)alloc((size_t)N_NODES * 4);
    int*   blockSums = (int*)alloc(512);
    int*   colsrc    = (int*)alloc((size_t)N_EDGES * 4);
    float* g1        = (float*)alloc((size_t)N_NODES * LAT * 4);
    float* g2        = (float*)alloc((size_t)N_NODES * 4 * 4);

    int nScanBlocks = (N_NODES + 1023) / 1024;

    hipMemsetAsync(cnt, 0, (size_t)N_NODES * 4, stream);
    k_count<<<(N_EDGES + 255) / 256, 256, 0, stream>>>(dstA, cnt);
    k_dinv<<<(N_NODES + 255) / 256, 256, 0, stream>>>(cnt, dinv);
    k_scan1<<<nScanBlocks, 256, 0, stream>>>(cnt, rowptr, blockSums);
    k_scan2<<<1, 64, 0, stream>>>(blockSums, nScanBlocks);
    k_scan3<<<(N_NODES + 255) / 256, 256, 0, stream>>>(rowptr, blockSums, cursor);
    k_scatter<<<(N_EDGES + 255) / 256, 256, 0, stream>>>(srcA, dstA, cursor, colsrc);
    k_gemm1<<<N_NODES / 32, 256, 0, stream>>>(z, mat, W1, dinv, g1);
    k_gather1<<<N_NODES / 4, 256, 0, stream>>>(g1, colsrc, rowptr, dinv, b1, W2, g2);
    k_gather2<<<(N_NODES + 255) / 256, 256, 0, stream>>>(g2, colsrc, rowptr, dinv, b2, out);
}

// Round 3
// 424.374 us; speedup vs baseline: 1.0121x; 1.0121x over previous
//
#include <hip/hip_runtime.h>

#define N_NODES 100000
#define N_EDGES 1600000
#define LAT 128
#define MAT 8
#define OUTC 3

// ---------------- CSR build ----------------

__global__ void k_count(const int* __restrict__ dst, int* __restrict__ cnt) {
    int e = blockIdx.x * blockDim.x + threadIdx.x;
    if (e < N_EDGES) atomicAdd(&cnt[dst[e]], 1);
}

__global__ void k_dinv(const int* __restrict__ cnt, float* __restrict__ dinv) {
    int i = blockIdx.x * blockDim.x + threadIdx.x;
    if (i < N_NODES) dinv[i] = rsqrtf((float)cnt[i] + 1.0f);  // +1 self-loop
}

// exclusive scan, 1024 elements per block (256 threads x 4)
__global__ __launch_bounds__(256) void k_scan1(const int* __restrict__ cnt,
                                               int* __restrict__ rowptr,
                                               int* __restrict__ blockSums) {
    __shared__ int wsum[4];
    int t = threadIdx.x;
    int lane = t & 63, w = t >> 6;
    int idx = blockIdx.x * 1024 + t * 4;
    int v0 = (idx + 0 < N_NODES) ? cnt[idx + 0] : 0;
    int v1 = (idx + 1 < N_NODES) ? cnt[idx + 1] : 0;
    int v2 = (idx + 2 < N_NODES) ? cnt[idx + 2] : 0;
    int v3 = (idx + 3 < N_NODES) ? cnt[idx + 3] : 0;
    int ts = v0 + v1 + v2 + v3;
    int x = ts;
#pragma unroll
    for (int off = 1; off < 64; off <<= 1) {
        int y = __shfl_up(x, off, 64);
        if (lane >= off) x += y;
    }
    if (lane == 63) wsum[w] = x;
    __syncthreads();
    int wo = 0;
#pragma unroll
    for (int i = 0; i < 4; ++i)
        if (i < w) wo += wsum[i];
    int base = wo + x - ts;  // exclusive prefix for this thread's first element
    if (idx + 0 < N_NODES) rowptr[idx + 0] = base;
    if (idx + 1 < N_NODES) rowptr[idx + 1] = base + v0;
    if (idx + 2 < N_NODES) rowptr[idx + 2] = base + v0 + v1;
    if (idx + 3 < N_NODES) rowptr[idx + 3] = base + v0 + v1 + v2;
    if (t == 255) blockSums[blockIdx.x] = wo + x;  // block total
}

__global__ void k_scan2(int* __restrict__ blockSums, int nb) {
    if (threadIdx.x == 0 && blockIdx.x == 0) {
        int run = 0;
        for (int i = 0; i < nb; ++i) { int v = blockSums[i]; blockSums[i] = run; run += v; }
    }
}

__global__ void k_scan3(int* __restrict__ rowptr, const int* __restrict__ blockSums,
                        int* __restrict__ cursor) {
    int i = blockIdx.x * blockDim.x + threadIdx.x;
    if (i < N_NODES) {
        int r = rowptr[i] + blockSums[i >> 10];
        rowptr[i] = r;
        cursor[i] = r;
    }
    if (i == 0) rowptr[N_NODES] = N_EDGES;
}

__global__ void k_scatter(const int* __restrict__ src, const int* __restrict__ dst,
                          int* __restrict__ cursor, int* __restrict__ colsrc) {
    int e = blockIdx.x * blockDim.x + threadIdx.x;
    if (e < N_EDGES) {
        int d = dst[e];
        int pos = atomicAdd(&cursor[d], 1);
        colsrc[pos] = src[e];
    }
}

// ---------------- GEMM1: g1 = (concat(z, mat) @ W1) * dinv[n] ----------------
// block = 256 threads, 32 nodes/block. thread -> group g = tid>>5 (4 nodes),
// output quad jq = (tid&31)*4. W1 (136x128 = 69.6KB) staged in LDS.
__global__ __launch_bounds__(256) void k_gemm1(const float* __restrict__ z,
                                               const float* __restrict__ mat,
                                               const float* __restrict__ W1,
                                               const float* __restrict__ dinv,
                                               float* __restrict__ g1) {
    __shared__ float w1s[(LAT + MAT) * LAT];
    for (int i = threadIdx.x; i < (LAT + MAT) * LAT; i += 256) w1s[i] = W1[i];
    __syncthreads();
    int g = threadIdx.x >> 5;
    int jq = (threadIdx.x & 31) * 4;
    int n0 = blockIdx.x * 32 + g * 4;
    float acc[4][4] = {{0.f}};
    // z part: k = 0..127
    for (int k4 = 0; k4 < 32; ++k4) {
        float w[4][4];
#pragma unroll
        for (int t = 0; t < 4; ++t)
            *(float4*)&w[t][0] = *(const float4*)&w1s[(k4 * 4 + t) * LAT + jq];
#pragma unroll
        for (int i = 0; i < 4; ++i) {
            float4 xv = *(const float4*)&z[(size_t)(n0 + i) * LAT + k4 * 4];
#pragma unroll
            for (int c = 0; c < 4; ++c)
                acc[i][c] += xv.x * w[0][c] + xv.y * w[1][c] + xv.z * w[2][c] + xv.w * w[3][c];
        }
    }
    // mat part: k = 128..135
#pragma unroll
    for (int h = 0; h < 2; ++h) {
        float w[4][4];
#pragma unroll
        for (int t = 0; t < 4; ++t)
            *(float4*)&w[t][0] = *(const float4*)&w1s[(LAT + h * 4 + t) * LAT + jq];
#pragma unroll
        for (int i = 0; i < 4; ++i) {
            float4 xv = *(const float4*)&mat[(size_t)(n0 + i) * MAT + h * 4];
#pragma unroll
            for (int c = 0; c < 4; ++c)
                acc[i][c] += xv.x * w[0][c] + xv.y * w[1][c] + xv.z * w[2][c] + xv.w * w[3][c];
        }
    }
#pragma unroll
    for (int i = 0; i < 4; ++i) {
        float d = dinv[n0 + i];
        float4 o = make_float4(acc[i][0] * d, acc[i][1] * d, acc[i][2] * d, acc[i][3] * d);
        *(float4*)&g1[(size_t)(n0 + i) * LAT + jq] = o;
    }
}

// ---------------- gather layer1 + fused 128x3 GEMM2 ----------------
// one wave per node; lane holds float2 of the 128-wide row.
// x1 = relu(dinv[n]*(g1[n] + sum g1[src]) + b1); g2[n] = (x1 @ W2) * dinv[n]
__global__ __launch_bounds__(256) void k_gather1(const float* __restrict__ g1,
                                                 const int* __restrict__ colsrc,
                                                 const int* __restrict__ rowptr,
                                                 const float* __restrict__ dinv,
                                                 const float* __restrict__ b1,
                                                 const float* __restrict__ W2,
                                                 float* __restrict__ g2) {
    int n = blockIdx.x * 4 + (threadIdx.x >> 6);
    int lane = threadIdx.x & 63;
    const float2* g1v = (const float2*)g1;
    float2 a = g1v[(size_t)n * 64 + lane];
    float ax = a.x, ay = a.y;
    int e = rowptr[n], eEnd = rowptr[n + 1];
    for (; e + 4 <= eEnd; e += 4) {
        int s0 = colsrc[e], s1 = colsrc[e + 1], s2 = colsrc[e + 2], s3 = colsrc[e + 3];
        float2 v0 = g1v[(size_t)s0 * 64 + lane];
        float2 v1 = g1v[(size_t)s1 * 64 + lane];
        float2 v2 = g1v[(size_t)s2 * 64 + lane];
        float2 v3 = g1v[(size_t)s3 * 64 + lane];
        ax += v0.x + v1.x + v2.x + v3.x;
        ay += v0.y + v1.y + v2.y + v3.y;
    }
    for (; e < eEnd; ++e) {
        int s = colsrc[e];
        float2 v = g1v[(size_t)s * 64 + lane];
        ax += v.x; ay += v.y;
    }
    float d = dinv[n];
    float2 bb = ((const float2*)b1)[lane];
    float x0 = fmaxf(ax * d + bb.x, 0.f);
    float x1 = fmaxf(ay * d + bb.y, 0.f);
    float p0 = x0 * W2[(2 * lane) * OUTC + 0] + x1 * W2[(2 * lane + 1) * OUTC + 0];
    float p1 = x0 * W2[(2 * lane) * OUTC + 1] + x1 * W2[(2 * lane + 1) * OUTC + 1];
    float p2 = x0 * W2[(2 * lane) * OUTC + 2] + x1 * W2[(2 * lane + 1) * OUTC + 2];
#pragma unroll
    for (int off = 32; off > 0; off >>= 1) {
        p0 += __shfl_down(p0, off, 64);
        p1 += __shfl_down(p1, off, 64);
        p2 += __shfl_down(p2, off, 64);
    }
    if (lane == 0) ((float4*)g2)[n] = make_float4(p0 * d, p1 * d, p2 * d, 0.f);
}

// ---------------- gather layer2: out = dinv[n]*(g2[n] + sum g2[src]) + b2 ----------------
__global__ void k_gather2(const float* __restrict__ g2, const int* __restrict__ colsrc,
                          const int* __restrict__ rowptr, const float* __restrict__ dinv,
                          const float* __restrict__ b2, float* __restrict__ out) {
    int n = blockIdx.x * blockDim.x + threadIdx.x;
    if (n >= N_NODES) return;
    const float4* gv = (const float4*)g2;
    float4 a = gv[n];
    float s0 = a.x, s1 = a.y, s2 = a.z;
    int eEnd = rowptr[n + 1];
    for (int e = rowptr[n]; e < eEnd; ++e) {
        float4 v = gv[colsrc[e]];
        s0 += v.x; s1 += v.y; s2 += v.z;
    }
    float d = dinv[n];
    out[(size_t)n * 3 + 0] = s0 * d + b2[0];
    out[(size_t)n * 3 + 1] = s1 * d + b2[1];
    out[(size_t)n * 3 + 2] = s2 * d + b2[2];
}

// ---------------- launch ----------------

extern "C" void kernel_launch(void* const* d_in, const int* in_sizes, int n_in,
                              void* d_out, int out_size, void* d_ws, size_t ws_size,
                              hipStream_t stream) {
    const float* z   = (const float*)d_in[0];
    const int*   ei  = (const int*)d_in[1];   // [2, E] int32
    const float* mat = (const float*)d_in[2];
    const float* W1  = (const float*)d_in[3];
    const float* b1  = (const float*)d_in[4];
    const float* W2  = (const float*)d_in[5];
    const float* b2  = (const float*)d_in[6];
    float* out = (float*)d_out;

    const int* srcA = ei;             // row 0 = message source
    const int* dstA = ei + N_EDGES;   // row 1 = message target

    char* ws = (char*)d_ws;
    auto alloc = [&](size_t bytes) {
        char* p = ws;
        ws += (bytes + 255) & ~(size_t)255;
        return p;
    };
    int*   cnt       = (int*)alloc((size_t)N_NODES * 4);
    int*   rowptr    = (int*)alloc((size_t)(N_NODES + 1) * 4);
    int*   cursor    = (int*)alloc((size_t)N_NODES * 4);
    float* dinv      = (float*)alloc((size_t)N_NODES * 4);
    int*   blockSums = (int*)alloc(512);
    int*   colsrc    = (int*)alloc((size_t)N_EDGES * 4);
    float* g1        = (float*)alloc((size_t)N_NODES * LAT * 4);
    float* g2        = (float*)alloc((size_t)N_NODES * 4 * 4);

    int nScanBlocks = (N_NODES + 1023) / 1024;

    hipMemsetAsync(cnt, 0, (size_t)N_NODES * 4, stream);
    k_count<<<(N_EDGES + 255) / 256, 256, 0, stream>>>(dstA, cnt);
    k_dinv<<<(N_NODES + 255) / 256, 256, 0, stream>>>(cnt, dinv);
    k_scan1<<<nScanBlocks, 256, 0, stream>>>(cnt, rowptr, blockSums);
    k_scan2<<<1, 64, 0, stream>>>(blockSums, nScanBlocks);
    k_scan3<<<(N_NODES + 255) / 256, 256, 0, stream>>>(rowptr, blockSums, cursor);
    k_scatter<<<(N_EDGES + 255) / 256, 256, 0, stream>>>(srcA, dstA, cursor, colsrc);
    k_gemm1<<<N_NODES / 32, 256, 0, stream>>>(z, mat, W1, dinv, g1);
    k_gather1<<<N_NODES / 4, 256, 0, stream>>>(g1, colsrc, rowptr, dinv, b1, W2, g2);
    k_gather2<<<(N_NODES + 255) / 256, 256, 0, stream>>>(g2, colsrc, rowptr, dinv, b2, out);
}

// Round 4
// 423.746 us; speedup vs baseline: 1.0136x; 1.0015x over previous
//
#include <hip/hip_runtime.h>

#define N_NODES 100000
#define N_EDGES 1600000
#define LAT 128
#define MAT 8
#define OUTC 3

// ---------------- CSR build ----------------

__global__ void k_count(const int* __restrict__ dst, int* __restrict__ cnt) {
    int e = blockIdx.x * blockDim.x + threadIdx.x;
    if (e < N_EDGES) atomicAdd(&cnt[dst[e]], 1);
}

__global__ void k_dinv(const int* __restrict__ cnt, float* __restrict__ dinv) {
    int i = blockIdx.x * blockDim.x + threadIdx.x;
    if (i < N_NODES) dinv[i] = rsqrtf((float)cnt[i] + 1.0f);  // +1 self-loop
}

// exclusive scan, 1024 elements per block (256 threads x 4)
__global__ __launch_bounds__(256) void k_scan1(const int* __restrict__ cnt,
                                               int* __restrict__ rowptr,
                                               int* __restrict__ blockSums) {
    __shared__ int wsum[4];
    int t = threadIdx.x;
    int lane = t & 63, w = t >> 6;
    int idx = blockIdx.x * 1024 + t * 4;
    int v0 = (idx + 0 < N_NODES) ? cnt[idx + 0] : 0;
    int v1 = (idx + 1 < N_NODES) ? cnt[idx + 1] : 0;
    int v2 = (idx + 2 < N_NODES) ? cnt[idx + 2] : 0;
    int v3 = (idx + 3 < N_NODES) ? cnt[idx + 3] : 0;
    int ts = v0 + v1 + v2 + v3;
    int x = ts;
#pragma unroll
    for (int off = 1; off < 64; off <<= 1) {
        int y = __shfl_up(x, off, 64);
        if (lane >= off) x += y;
    }
    if (lane == 63) wsum[w] = x;
    __syncthreads();
    int wo = 0;
#pragma unroll
    for (int i = 0; i < 4; ++i)
        if (i < w) wo += wsum[i];
    int base = wo + x - ts;  // exclusive prefix for this thread's first element
    if (idx + 0 < N_NODES) rowptr[idx + 0] = base;
    if (idx + 1 < N_NODES) rowptr[idx + 1] = base + v0;
    if (idx + 2 < N_NODES) rowptr[idx + 2] = base + v0 + v1;
    if (idx + 3 < N_NODES) rowptr[idx + 3] = base + v0 + v1 + v2;
    if (t == 255) blockSums[blockIdx.x] = wo + x;  // block total
}

__global__ void k_scan2(int* __restrict__ blockSums, int nb) {
    if (threadIdx.x == 0 && blockIdx.x == 0) {
        int run = 0;
        for (int i = 0; i < nb; ++i) { int v = blockSums[i]; blockSums[i] = run; run += v; }
    }
}

__global__ void k_scan3(int* __restrict__ rowptr, const int* __restrict__ blockSums,
                        int* __restrict__ cursor) {
    int i = blockIdx.x * blockDim.x + threadIdx.x;
    if (i < N_NODES) {
        int r = rowptr[i] + blockSums[i >> 10];
        rowptr[i] = r;
        cursor[i] = r;
    }
    if (i == 0) rowptr[N_NODES] = N_EDGES;
}

__global__ void k_scatter(const int* __restrict__ src, const int* __restrict__ dst,
                          int* __restrict__ cursor, int* __restrict__ colsrc) {
    int e = blockIdx.x * blockDim.x + threadIdx.x;
    if (e < N_EDGES) {
        int d = dst[e];
        int pos = atomicAdd(&cursor[d], 1);
        colsrc[pos] = src[e];
    }
}

// ---------------- GEMM1: g1 = (concat(z, mat) @ W1) * dinv[n] ----------------
// block = 256 threads, 32 nodes/block. thread -> group g = tid>>5 (4 nodes),
// output quad jq = (tid&31)*4. W1 (136x128 = 69.6KB) staged in LDS.
__global__ __launch_bounds__(256) void k_gemm1(const float* __restrict__ z,
                                               const float* __restrict__ mat,
                                               const float* __restrict__ W1,
                                               const float* __restrict__ dinv,
                                               float* __restrict__ g1) {
    __shared__ float w1s[(LAT + MAT) * LAT];
    for (int i = threadIdx.x; i < (LAT + MAT) * LAT; i += 256) w1s[i] = W1[i];
    __syncthreads();
    int g = threadIdx.x >> 5;
    int jq = (threadIdx.x & 31) * 4;
    int n0 = blockIdx.x * 32 + g * 4;
    float acc[4][4] = {{0.f}};
    // z part: k = 0..127
    for (int k4 = 0; k4 < 32; ++k4) {
        float w[4][4];
#pragma unroll
        for (int t = 0; t < 4; ++t)
            *(float4*)&w[t][0] = *(const float4*)&w1s[(k4 * 4 + t) * LAT + jq];
#pragma unroll
        for (int i = 0; i < 4; ++i) {
            float4 xv = *(const float4*)&z[(size_t)(n0 + i) * LAT + k4 * 4];
#pragma unroll
            for (int c = 0; c < 4; ++c)
                acc[i][c] += xv.x * w[0][c] + xv.y * w[1][c] + xv.z * w[2][c] + xv.w * w[3][c];
        }
    }
    // mat part: k = 128..135
#pragma unroll
    for (int h = 0; h < 2; ++h) {
        float w[4][4];
#pragma unroll
        for (int t = 0; t < 4; ++t)
            *(float4*)&w[t][0] = *(const float4*)&w1s[(LAT + h * 4 + t) * LAT + jq];
#pragma unroll
        for (int i = 0; i < 4; ++i) {
            float4 xv = *(const float4*)&mat[(size_t)(n0 + i) * MAT + h * 4];
#pragma unroll
            for (int c = 0; c < 4; ++c)
                acc[i][c] += xv.x * w[0][c] + xv.y * w[1][c] + xv.z * w[2][c] + xv.w * w[3][c];
        }
    }
#pragma unroll
    for (int i = 0; i < 4; ++i) {
        float d = dinv[n0 + i];
        float4 o = make_float4(acc[i][0] * d, acc[i][1] * d, acc[i][2] * d, acc[i][3] * d);
        *(float4*)&g1[(size_t)(n0 + i) * LAT + jq] = o;
    }
}

// ---------------- gather layer1 + fused 128x3 GEMM2 ----------------
// one wave per node; lane holds float2 of the 128-wide row.
// x1 = relu(dinv[n]*(g1[n] + sum g1[src]) + b1); g2[n] = (x1 @ W2) * dinv[n]
__global__ __launch_bounds__(256) void k_gather1(const float* __restrict__ g1,
                                                 const int* __restrict__ colsrc,
                                                 const int* __restrict__ rowptr,
                                                 const float* __restrict__ dinv,
                                                 const float* __restrict__ b1,
                                                 const float* __restrict__ W2,
                                                 float* __restrict__ g2) {
    int n = blockIdx.x * 4 + (threadIdx.x >> 6);
    int lane = threadIdx.x & 63;
    const float2* g1v = (const float2*)g1;
    float2 a = g1v[(size_t)n * 64 + lane];
    float ax = a.x, ay = a.y;
    int e = rowptr[n], eEnd = rowptr[n + 1];
    for (; e + 4 <= eEnd; e += 4) {
        int s0 = colsrc[e], s1 = colsrc[e + 1], s2 = colsrc[e + 2], s3 = colsrc[e + 3];
        float2 v0 = g1v[(size_t)s0 * 64 + lane];
        float2 v1 = g1v[(size_t)s1 * 64 + lane];
        float2 v2 = g1v[(size_t)s2 * 64 + lane];
        float2 v3 = g1v[(size_t)s3 * 64 + lane];
        ax += v0.x + v1.x + v2.x + v3.x;
        ay += v0.y + v1.y + v2.y + v3.y;
    }
    for (; e < eEnd; ++e) {
        int s = colsrc[e];
        float2 v = g1v[(size_t)s * 64 + lane];
        ax += v.x; ay += v.y;
    }
    float d = dinv[n];
    float2 bb = ((const float2*)b1)[lane];
    float x0 = fmaxf(ax * d + bb.x, 0.f);
    float x1 = fmaxf(ay * d + bb.y, 0.f);
    float p0 = x0 * W2[(2 * lane) * OUTC + 0] + x1 * W2[(2 * lane + 1) * OUTC + 0];
    float p1 = x0 * W2[(2 * lane) * OUTC + 1] + x1 * W2[(2 * lane + 1) * OUTC + 1];
    float p2 = x0 * W2[(2 * lane) * OUTC + 2] + x1 * W2[(2 * lane + 1) * OUTC + 2];
#pragma unroll
    for (int off = 32; off > 0; off >>= 1) {
        p0 += __shfl_down(p0, off, 64);
        p1 += __shfl_down(p1, off, 64);
        p2 += __shfl_down(p2, off, 64);
    }
    if (lane == 0) ((float4*)g2)[n] = make_float4(p0 * d, p1 * d, p2 * d, 0.f);
}

// ---------------- gather layer2: out = dinv[n]*(g2[n] + sum g2[src]) + b2 ----------------
__global__ void k_gather2(const float* __restrict__ g2, const int* __restrict__ colsrc,
                          const int* __restrict__ rowptr, const float* __restrict__ dinv,
                          const float* __restrict__ b2, float* __restrict__ out) {
    int n = blockIdx.x * blockDim.x + threadIdx.x;
    if (n >= N_NODES) return;
    const float4* gv = (const float4*)g2;
    float4 a = gv[n];
    float s0 = a.x, s1 = a.y, s2 = a.z;
    int eEnd = rowptr[n + 1];
    for (int e = rowptr[n]; e < eEnd; ++e) {
        float4 v = gv[colsrc[e]];
        s0 += v.x; s1 += v.y; s2 += v.z;
    }
    float d = dinv[n];
    out[(size_t)n * 3 + 0] = s0 * d + b2[0];
    out[(size_t)n * 3 + 1] = s1 * d + b2[1];
    out[(size_t)n * 3 + 2] = s2 * d + b2[2];
}

// ---------------- launch ----------------

extern "C" void kernel_launch(void* const* d_in, const int* in_sizes, int n_in,
                              void* d_out, int out_size, void* d_ws, size_t ws_size,
                              hipStream_t stream) {
    const float* z   = (const float*)d_in[0];
    const int*   ei  = (const int*)d_in[1];   // [2, E] int32
    const float* mat = (const float*)d_in[2];
    const float* W1  = (const float*)d_in[3];
    const float* b1  = (const float*)d_in[4];
    const float* W2  = (const float*)d_in[5];
    const float* b2  = (const float*)d_in[6];
    float* out = (float*)d_out;

    const int* srcA = ei;             // row 0 = message source
    const int* dstA = ei + N_EDGES;   // row 1 = message target

    char* ws = (char*)d_ws;
    auto alloc = [&](size_t bytes) {
        char* p = ws;
        ws += (bytes + 255) & ~(size_t)255;
        return p;
    };
    int*   cnt       = (int*)alloc((size_t)N_NODES * 4);
    int*   rowptr    = (int*)alloc((size_t)(N_NODES + 1) * 4);
    int*   cursor    = (int*)alloc((size_t)N_NODES * 4);
    float* dinv      = (float*)alloc((size_t)N_NODES * 4);
    int*   blockSums = (int*)alloc(512);
    int*   colsrc    = (int*)alloc((size_t)N_EDGES * 4);
    float* g1        = (float*)alloc((size_t)N_NODES * LAT * 4);
    float* g2        = (float*)alloc((size_t)N_NODES * 4 * 4);

    int nScanBlocks = (N_NODES + 1023) / 1024;

    hipMemsetAsync(cnt, 0, (size_t)N_NODES * 4, stream);
    k_count<<<(N_EDGES + 255) / 256, 256, 0, stream>>>(dstA, cnt);
    k_dinv<<<(N_NODES + 255) / 256, 256, 0, stream>>>(cnt, dinv);
    k_scan1<<<nScanBlocks, 256, 0, stream>>>(cnt, rowptr, blockSums);
    k_scan2<<<1, 64, 0, stream>>>(blockSums, nScanBlocks);
    k_scan3<<<(N_NODES + 255) / 256, 256, 0, stream>>>(rowptr, blockSums, cursor);
    k_scatter<<<(N_EDGES + 255) / 256, 256, 0, stream>>>(srcA, dstA, cursor, colsrc);
    k_gemm1<<<N_NODES / 32, 256, 0, stream>>>(z, mat, W1, dinv, g1);
    k_gather1<<<N_NODES / 4, 256, 0, stream>>>(g1, colsrc, rowptr, dinv, b1, W2, g2);
    k_gather2<<<(N_NODES + 255) / 256, 256, 0, stream>>>(g2, colsrc, rowptr, dinv, b2, out);
}

// Round 5
// 254.448 us; speedup vs baseline: 1.6880x; 1.6654x over previous
//
#include <hip/hip_runtime.h>

#define N_NODES 100000
#define N_EDGES 1600000
#define LAT 128
#define MAT 8
#define OUTC 3

#define NBKT 391          // ceil(N_NODES / 256) buckets of 256 nodes
#define CAP  4608         // per-bucket region capacity (mean 4096, sigma 64)
#define CHUNK 4096        // edges per binA block

// ---------------- Pass A: coarse bin by dst>>8, LDS-staged for coalesced writes ----------------
__global__ __launch_bounds__(256) void k_binA(const int* __restrict__ src,
                                              const int* __restrict__ dst,
                                              int* __restrict__ gcount,
                                              unsigned int* __restrict__ binned) {
    __shared__ int hist[NBKT];
    __shared__ int adj[NBKT];            // gbase - local_exclusive_prefix
    __shared__ int cur[NBKT];            // local scatter cursor
    __shared__ int wsum[4];
    __shared__ unsigned int lbuf[CHUNK];
    __shared__ unsigned short lbkt[CHUNK];

    int t = threadIdx.x;
    int base = blockIdx.x * CHUNK;
    int nEdge = min(CHUNK, N_EDGES - base);

    for (int i = t; i < NBKT; i += 256) hist[i] = 0;
    __syncthreads();

    unsigned int pk[16];
    unsigned short bk[16];
#pragma unroll
    for (int j = 0; j < 16; ++j) {
        int li = j * 256 + t;
        if (li < nEdge) {
            int e = base + li;
            int d = dst[e];
            int s = src[e];
            pk[j] = ((unsigned int)s << 8) | (unsigned int)(d & 255);
            bk[j] = (unsigned short)(d >> 8);
            atomicAdd(&hist[bk[j]], 1);
        } else {
            bk[j] = 0xffffu;
        }
    }
    __syncthreads();

    // exclusive scan over 391 buckets: each thread owns pair (2t, 2t+1)
    int lane = t & 63, w = t >> 6;
    int i0 = 2 * t, i1 = 2 * t + 1;
    int h0 = (i0 < NBKT) ? hist[i0] : 0;
    int h1 = (i1 < NBKT) ? hist[i1] : 0;
    int ps = h0 + h1;
    int x = ps;
#pragma unroll
    for (int off = 1; off < 64; off <<= 1) {
        int y = __shfl_up(x, off, 64);
        if (lane >= off) x += y;
    }
    if (lane == 63) wsum[w] = x;
    __syncthreads();
    int woff = 0;
#pragma unroll
    for (int i = 0; i < 4; ++i)
        if (i < w) woff += wsum[i];
    int excl = woff + x - ps;   // exclusive prefix of element i0
    if (i0 < NBKT) {
        int g0 = i0 * CAP + atomicAdd(&gcount[i0], h0);
        adj[i0] = g0 - excl;
        cur[i0] = excl;
    }
    if (i1 < NBKT) {
        int g1r = i1 * CAP + atomicAdd(&gcount[i1], h1);
        adj[i1] = g1r - (excl + h0);
        cur[i1] = excl + h0;
    }
    __syncthreads();

    // local scatter into bucket-sorted LDS order
#pragma unroll
    for (int j = 0; j < 16; ++j) {
        if (bk[j] != 0xffffu) {
            int pos = atomicAdd(&cur[bk[j]], 1);
            lbuf[pos] = pk[j];
            lbkt[pos] = bk[j];
        }
    }
    __syncthreads();

    // linear, coalesced write-out: contiguous within-bucket chunks
    for (int i = t; i < nEdge; i += 256) {
        int b = lbkt[i];
        binned[adj[b] + i] = lbuf[i];
    }
}

// ---------------- scan of 391 bucket counts -> bucketBase ----------------
__global__ __launch_bounds__(256) void k_bscan(const int* __restrict__ gcount,
                                               int* __restrict__ bucketBase,
                                               int* __restrict__ rowptr) {
    __shared__ int wsum[4];
    int t = threadIdx.x;
    int lane = t & 63, w = t >> 6;
    int i0 = 2 * t, i1 = 2 * t + 1;
    int h0 = (i0 < NBKT) ? gcount[i0] : 0;
    int h1 = (i1 < NBKT) ? gcount[i1] : 0;
    int ps = h0 + h1;
    int x = ps;
#pragma unroll
    for (int off = 1; off < 64; off <<= 1) {
        int y = __shfl_up(x, off, 64);
        if (lane >= off) x += y;
    }
    if (lane == 63) wsum[w] = x;
    __syncthreads();
    int woff = 0;
#pragma unroll
    for (int i = 0; i < 4; ++i)
        if (i < w) woff += wsum[i];
    int excl = woff + x - ps;
    bucketBase[i0] = excl;
    bucketBase[i1] = excl + h0;
    if (t == 0) rowptr[N_NODES] = N_EDGES;
}

// ---------------- Pass B: fine sort within bucket, emit colsrc + rowptr + dinv ----------------
__global__ __launch_bounds__(256) void k_binB(const unsigned int* __restrict__ binned,
                                              const int* __restrict__ gcount,
                                              const int* __restrict__ bucketBase,
                                              int* __restrict__ colsrc,
                                              int* __restrict__ rowptr,
                                              float* __restrict__ dinv) {
    __shared__ unsigned int lbuf[CAP];
    __shared__ int lsrc[CAP];
    __shared__ int hist[256];
    __shared__ int cur[256];
    __shared__ int wsum[4];

    int b = blockIdx.x, t = threadIdx.x;
    int cnt = min(gcount[b], CAP);
    int gb = bucketBase[b];
    const unsigned int* bp = binned + (size_t)b * CAP;

    for (int i = t; i < cnt; i += 256) lbuf[i] = bp[i];
    hist[t] = 0;
    __syncthreads();
    for (int i = t; i < cnt; i += 256) atomicAdd(&hist[lbuf[i] & 255], 1);
    __syncthreads();

    // exclusive scan of hist[256]
    int lane = t & 63, w = t >> 6;
    int h = hist[t];
    int x = h;
#pragma unroll
    for (int off = 1; off < 64; off <<= 1) {
        int y = __shfl_up(x, off, 64);
        if (lane >= off) x += y;
    }
    if (lane == 63) wsum[w] = x;
    __syncthreads();
    int woff = 0;
#pragma unroll
    for (int i = 0; i < 4; ++i)
        if (i < w) woff += wsum[i];
    int excl = woff + x - h;
    cur[t] = excl;

    int node = b * 256 + t;
    if (node < N_NODES) {
        rowptr[node] = gb + excl;
        dinv[node] = rsqrtf((float)h + 1.0f);   // +1 self-loop
    }
    __syncthreads();

    for (int i = t; i < cnt; i += 256) {
        unsigned int p = lbuf[i];
        int pos = atomicAdd(&cur[p & 255], 1);
        lsrc[pos] = (int)(p >> 8);
    }
    __syncthreads();

    for (int i = t; i < cnt; i += 256) colsrc[gb + i] = lsrc[i];
}

// ---------------- GEMM1: g1 = (concat(z, mat) @ W1) * dinv[n] ----------------
__global__ __launch_bounds__(256) void k_gemm1(const float* __restrict__ z,
                                               const float* __restrict__ mat,
                                               const float* __restrict__ W1,
                                               const float* __restrict__ dinv,
                                               float* __restrict__ g1) {
    __shared__ float w1s[(LAT + MAT) * LAT];
    for (int i = threadIdx.x; i < (LAT + MAT) * LAT; i += 256) w1s[i] = W1[i];
    __syncthreads();
    int g = threadIdx.x >> 5;
    int jq = (threadIdx.x & 31) * 4;
    int n0 = blockIdx.x * 32 + g * 4;
    float acc[4][4] = {{0.f}};
    for (int k4 = 0; k4 < 32; ++k4) {
        float w[4][4];
#pragma unroll
        for (int t = 0; t < 4; ++t)
            *(float4*)&w[t][0] = *(const float4*)&w1s[(k4 * 4 + t) * LAT + jq];
#pragma unroll
        for (int i = 0; i < 4; ++i) {
            float4 xv = *(const float4*)&z[(size_t)(n0 + i) * LAT + k4 * 4];
#pragma unroll
            for (int c = 0; c < 4; ++c)
                acc[i][c] += xv.x * w[0][c] + xv.y * w[1][c] + xv.z * w[2][c] + xv.w * w[3][c];
        }
    }
#pragma unroll
    for (int h = 0; h < 2; ++h) {
        float w[4][4];
#pragma unroll
        for (int t = 0; t < 4; ++t)
            *(float4*)&w[t][0] = *(const float4*)&w1s[(LAT + h * 4 + t) * LAT + jq];
#pragma unroll
        for (int i = 0; i < 4; ++i) {
            float4 xv = *(const float4*)&mat[(size_t)(n0 + i) * MAT + h * 4];
#pragma unroll
            for (int c = 0; c < 4; ++c)
                acc[i][c] += xv.x * w[0][c] + xv.y * w[1][c] + xv.z * w[2][c] + xv.w * w[3][c];
        }
    }
#pragma unroll
    for (int i = 0; i < 4; ++i) {
        float d = dinv[n0 + i];
        float4 o = make_float4(acc[i][0] * d, acc[i][1] * d, acc[i][2] * d, acc[i][3] * d);
        *(float4*)&g1[(size_t)(n0 + i) * LAT + jq] = o;
    }
}

// ---------------- gather layer1 + fused 128x3 GEMM2 ----------------
__global__ __launch_bounds__(256) void k_gather1(const float* __restrict__ g1,
                                                 const int* __restrict__ colsrc,
                                                 const int* __restrict__ rowptr,
                                                 const float* __restrict__ dinv,
                                                 const float* __restrict__ b1,
                                                 const float* __restrict__ W2,
                                                 float* __restrict__ g2) {
    int n = blockIdx.x * 4 + (threadIdx.x >> 6);
    int lane = threadIdx.x & 63;
    const float2* g1v = (const float2*)g1;
    float2 a = g1v[(size_t)n * 64 + lane];
    float ax = a.x, ay = a.y;
    int e = rowptr[n], eEnd = rowptr[n + 1];
    for (; e + 4 <= eEnd; e += 4) {
        int s0 = colsrc[e], s1 = colsrc[e + 1], s2 = colsrc[e + 2], s3 = colsrc[e + 3];
        float2 v0 = g1v[(size_t)s0 * 64 + lane];
        float2 v1 = g1v[(size_t)s1 * 64 + lane];
        float2 v2 = g1v[(size_t)s2 * 64 + lane];
        float2 v3 = g1v[(size_t)s3 * 64 + lane];
        ax += v0.x + v1.x + v2.x + v3.x;
        ay += v0.y + v1.y + v2.y + v3.y;
    }
    for (; e < eEnd; ++e) {
        int s = colsrc[e];
        float2 v = g1v[(size_t)s * 64 + lane];
        ax += v.x; ay += v.y;
    }
    float d = dinv[n];
    float2 bb = ((const float2*)b1)[lane];
    float x0 = fmaxf(ax * d + bb.x, 0.f);
    float x1 = fmaxf(ay * d + bb.y, 0.f);
    float p0 = x0 * W2[(2 * lane) * OUTC + 0] + x1 * W2[(2 * lane + 1) * OUTC + 0];
    float p1 = x0 * W2[(2 * lane) * OUTC + 1] + x1 * W2[(2 * lane + 1) * OUTC + 1];
    float p2 = x0 * W2[(2 * lane) * OUTC + 2] + x1 * W2[(2 * lane + 1) * OUTC + 2];
#pragma unroll
    for (int off = 32; off > 0; off >>= 1) {
        p0 += __shfl_down(p0, off, 64);
        p1 += __shfl_down(p1, off, 64);
        p2 += __shfl_down(p2, off, 64);
    }
    if (lane == 0) ((float4*)g2)[n] = make_float4(p0 * d, p1 * d, p2 * d, 0.f);
}

// ---------------- gather layer2: out = dinv[n]*(g2[n] + sum g2[src]) + b2 ----------------
__global__ void k_gather2(const float* __restrict__ g2, const int* __restrict__ colsrc,
                          const int* __restrict__ rowptr, const float* __restrict__ dinv,
                          const float* __restrict__ b2, float* __restrict__ out) {
    int n = blockIdx.x * blockDim.x + threadIdx.x;
    if (n >= N_NODES) return;
    const float4* gv = (const float4*)g2;
    float4 a = gv[n];
    float s0 = a.x, s1 = a.y, s2 = a.z;
    int eEnd = rowptr[n + 1];
    for (int e = rowptr[n]; e < eEnd; ++e) {
        float4 v = gv[colsrc[e]];
        s0 += v.x; s1 += v.y; s2 += v.z;
    }
    float d = dinv[n];
    out[(size_t)n * 3 + 0] = s0 * d + b2[0];
    out[(size_t)n * 3 + 1] = s1 * d + b2[1];
    out[(size_t)n * 3 + 2] = s2 * d + b2[2];
}

// ---------------- launch ----------------

extern "C" void kernel_launch(void* const* d_in, const int* in_sizes, int n_in,
                              void* d_out, int out_size, void* d_ws, size_t ws_size,
                              hipStream_t stream) {
    const float* z   = (const float*)d_in[0];
    const int*   ei  = (const int*)d_in[1];   // [2, E] int32
    const float* mat = (const float*)d_in[2];
    const float* W1  = (const float*)d_in[3];
    const float* b1  = (const float*)d_in[4];
    const float* W2  = (const float*)d_in[5];
    const float* b2  = (const float*)d_in[6];
    float* out = (float*)d_out;

    const int* srcA = ei;             // row 0 = message source
    const int* dstA = ei + N_EDGES;   // row 1 = message target

    char* ws = (char*)d_ws;
    auto alloc = [&](size_t bytes) {
        char* p = ws;
        ws += (bytes + 255) & ~(size_t)255;
        return p;
    };
    int*   gcount     = (int*)alloc(512 * 4);
    int*   bucketBase = (int*)alloc(512 * 4);
    int*   rowptr     = (int*)alloc((size_t)(N_NODES + 1) * 4);
    float* dinv       = (float*)alloc((size_t)N_NODES * 4);
    int*   colsrc     = (int*)alloc((size_t)N_EDGES * 4);
    float* g1         = (float*)alloc((size_t)N_NODES * LAT * 4);
    float* g2         = (float*)alloc((size_t)N_NODES * 4 * 4);
    // binned (7.2 MB) aliases g1 (51.2 MB): lifetimes are disjoint
    // (binned: binA->binB; g1: gemm1->gather1, after binB completes)
    unsigned int* binned = (unsigned int*)g1;

    hipMemsetAsync(gcount, 0, 512 * 4, stream);
    int nBlocksA = (N_EDGES + CHUNK - 1) / CHUNK;  // 391
    k_binA<<<nBlocksA, 256, 0, stream>>>(srcA, dstA, gcount, binned);
    k_bscan<<<1, 256, 0, stream>>>(gcount, bucketBase, rowptr);
    k_binB<<<NBKT, 256, 0, stream>>>(binned, gcount, bucketBase, colsrc, rowptr, dinv);
    k_gemm1<<<N_NODES / 32, 256, 0, stream>>>(z, mat, W1, dinv, g1);
    k_gather1<<<N_NODES / 4, 256, 0, stream>>>(g1, colsrc, rowptr, dinv, b1, W2, g2);
    k_gather2<<<(N_NODES + 255) / 256, 256, 0, stream>>>(g2, colsrc, rowptr, dinv, b2, out);
}

// Round 6
// 208.899 us; speedup vs baseline: 2.0560x; 1.2180x over previous
//
#include <hip/hip_runtime.h>

#define N_NODES 100000
#define N_EDGES 1600000
#define LAT 128
#define MAT 8
#define OUTC 3

#define NBKT 391          // ceil(N_NODES / 256) buckets of 256 nodes
#define CAP  4608         // per-bucket region capacity (mean 4096, sigma 64)
#define CHUNK 4096        // edges per binA block

__device__ __forceinline__ unsigned int pack_bf16(float a, float b) {
    unsigned int ua = __float_as_uint(a);
    ua = (ua + 0x7fffu + ((ua >> 16) & 1u)) >> 16;      // RTNE
    unsigned int ub = __float_as_uint(b);
    ub = (ub + 0x7fffu + ((ub >> 16) & 1u)) >> 16;
    return ua | (ub << 16);
}

// ---------------- Pass A: coarse bin by dst>>8, LDS-staged for coalesced writes ----------------
__global__ __launch_bounds__(256) void k_binA(const int* __restrict__ src,
                                              const int* __restrict__ dst,
                                              int* __restrict__ gcount,
                                              unsigned int* __restrict__ binned) {
    __shared__ int hist[NBKT];
    __shared__ int adj[NBKT];            // gbase - local_exclusive_prefix
    __shared__ int cur[NBKT];            // local scatter cursor
    __shared__ int wsum[4];
    __shared__ unsigned int lbuf[CHUNK];
    __shared__ unsigned short lbkt[CHUNK];

    int t = threadIdx.x;
    int base = blockIdx.x * CHUNK;
    int nEdge = min(CHUNK, N_EDGES - base);

    for (int i = t; i < NBKT; i += 256) hist[i] = 0;
    __syncthreads();

    unsigned int pk[16];
    unsigned short bk[16];
#pragma unroll
    for (int j = 0; j < 16; ++j) {
        int li = j * 256 + t;
        if (li < nEdge) {
            int e = base + li;
            int d = dst[e];
            int s = src[e];
            pk[j] = ((unsigned int)s << 8) | (unsigned int)(d & 255);
            bk[j] = (unsigned short)(d >> 8);
            atomicAdd(&hist[bk[j]], 1);
        } else {
            bk[j] = 0xffffu;
        }
    }
    __syncthreads();

    // exclusive scan over 391 buckets: each thread owns pair (2t, 2t+1)
    int lane = t & 63, w = t >> 6;
    int i0 = 2 * t, i1 = 2 * t + 1;
    int h0 = (i0 < NBKT) ? hist[i0] : 0;
    int h1 = (i1 < NBKT) ? hist[i1] : 0;
    int ps = h0 + h1;
    int x = ps;
#pragma unroll
    for (int off = 1; off < 64; off <<= 1) {
        int y = __shfl_up(x, off, 64);
        if (lane >= off) x += y;
    }
    if (lane == 63) wsum[w] = x;
    __syncthreads();
    int woff = 0;
#pragma unroll
    for (int i = 0; i < 4; ++i)
        if (i < w) woff += wsum[i];
    int excl = woff + x - ps;   // exclusive prefix of element i0
    if (i0 < NBKT) {
        int g0 = i0 * CAP + atomicAdd(&gcount[i0], h0);
        adj[i0] = g0 - excl;
        cur[i0] = excl;
    }
    if (i1 < NBKT) {
        int g1r = i1 * CAP + atomicAdd(&gcount[i1], h1);
        adj[i1] = g1r - (excl + h0);
        cur[i1] = excl + h0;
    }
    __syncthreads();

    // local scatter into bucket-sorted LDS order
#pragma unroll
    for (int j = 0; j < 16; ++j) {
        if (bk[j] != 0xffffu) {
            int pos = atomicAdd(&cur[bk[j]], 1);
            lbuf[pos] = pk[j];
            lbkt[pos] = bk[j];
        }
    }
    __syncthreads();

    // linear, coalesced write-out: contiguous within-bucket chunks
    for (int i = t; i < nEdge; i += 256) {
        int b = lbkt[i];
        binned[adj[b] + i] = lbuf[i];
    }
}

// ---------------- scan of 391 bucket counts -> bucketBase ----------------
__global__ __launch_bounds__(256) void k_bscan(const int* __restrict__ gcount,
                                               int* __restrict__ bucketBase,
                                               int* __restrict__ rowptr) {
    __shared__ int wsum[4];
    int t = threadIdx.x;
    int lane = t & 63, w = t >> 6;
    int i0 = 2 * t, i1 = 2 * t + 1;
    int h0 = (i0 < NBKT) ? gcount[i0] : 0;
    int h1 = (i1 < NBKT) ? gcount[i1] : 0;
    int ps = h0 + h1;
    int x = ps;
#pragma unroll
    for (int off = 1; off < 64; off <<= 1) {
        int y = __shfl_up(x, off, 64);
        if (lane >= off) x += y;
    }
    if (lane == 63) wsum[w] = x;
    __syncthreads();
    int woff = 0;
#pragma unroll
    for (int i = 0; i < 4; ++i)
        if (i < w) woff += wsum[i];
    int excl = woff + x - ps;
    bucketBase[i0] = excl;
    bucketBase[i1] = excl + h0;
    if (t == 0) rowptr[N_NODES] = N_EDGES;
}

// ---------------- Pass B: fine sort within bucket, emit colsrc + rowptr + dinv ----------------
__global__ __launch_bounds__(256) void k_binB(const unsigned int* __restrict__ binned,
                                              const int* __restrict__ gcount,
                                              const int* __restrict__ bucketBase,
                                              int* __restrict__ colsrc,
                                              int* __restrict__ rowptr,
                                              float* __restrict__ dinv) {
    __shared__ unsigned int lbuf[CAP];
    __shared__ int lsrc[CAP];
    __shared__ int hist[256];
    __shared__ int cur[256];
    __shared__ int wsum[4];

    int b = blockIdx.x, t = threadIdx.x;
    int cnt = min(gcount[b], CAP);
    int gb = bucketBase[b];
    const unsigned int* bp = binned + (size_t)b * CAP;

    for (int i = t; i < cnt; i += 256) lbuf[i] = bp[i];
    hist[t] = 0;
    __syncthreads();
    for (int i = t; i < cnt; i += 256) atomicAdd(&hist[lbuf[i] & 255], 1);
    __syncthreads();

    // exclusive scan of hist[256]
    int lane = t & 63, w = t >> 6;
    int h = hist[t];
    int x = h;
#pragma unroll
    for (int off = 1; off < 64; off <<= 1) {
        int y = __shfl_up(x, off, 64);
        if (lane >= off) x += y;
    }
    if (lane == 63) wsum[w] = x;
    __syncthreads();
    int woff = 0;
#pragma unroll
    for (int i = 0; i < 4; ++i)
        if (i < w) woff += wsum[i];
    int excl = woff + x - h;
    cur[t] = excl;

    int node = b * 256 + t;
    if (node < N_NODES) {
        rowptr[node] = gb + excl;
        dinv[node] = rsqrtf((float)h + 1.0f);   // +1 self-loop
    }
    __syncthreads();

    for (int i = t; i < cnt; i += 256) {
        unsigned int p = lbuf[i];
        int pos = atomicAdd(&cur[p & 255], 1);
        lsrc[pos] = (int)(p >> 8);
    }
    __syncthreads();

    for (int i = t; i < cnt; i += 256) colsrc[gb + i] = lsrc[i];
}

// ---------------- GEMM1: g1h = bf16( (concat(z, mat) @ W1) * dinv[n] ) ----------------
// packed 2x bf16 per uint; row = 64 uints = 256 B
__global__ __launch_bounds__(256) void k_gemm1(const float* __restrict__ z,
                                               const float* __restrict__ mat,
                                               const float* __restrict__ W1,
                                               const float* __restrict__ dinv,
                                               unsigned int* __restrict__ g1h) {
    __shared__ float w1s[(LAT + MAT) * LAT];
    for (int i = threadIdx.x; i < (LAT + MAT) * LAT; i += 256) w1s[i] = W1[i];
    __syncthreads();
    int g = threadIdx.x >> 5;
    int jq = (threadIdx.x & 31) * 4;
    int n0 = blockIdx.x * 32 + g * 4;
    float acc[4][4] = {{0.f}};
    for (int k4 = 0; k4 < 32; ++k4) {
        float w[4][4];
#pragma unroll
        for (int t = 0; t < 4; ++t)
            *(float4*)&w[t][0] = *(const float4*)&w1s[(k4 * 4 + t) * LAT + jq];
#pragma unroll
        for (int i = 0; i < 4; ++i) {
            float4 xv = *(const float4*)&z[(size_t)(n0 + i) * LAT + k4 * 4];
#pragma unroll
            for (int c = 0; c < 4; ++c)
                acc[i][c] += xv.x * w[0][c] + xv.y * w[1][c] + xv.z * w[2][c] + xv.w * w[3][c];
        }
    }
#pragma unroll
    for (int h = 0; h < 2; ++h) {
        float w[4][4];
#pragma unroll
        for (int t = 0; t < 4; ++t)
            *(float4*)&w[t][0] = *(const float4*)&w1s[(LAT + h * 4 + t) * LAT + jq];
#pragma unroll
        for (int i = 0; i < 4; ++i) {
            float4 xv = *(const float4*)&mat[(size_t)(n0 + i) * MAT + h * 4];
#pragma unroll
            for (int c = 0; c < 4; ++c)
                acc[i][c] += xv.x * w[0][c] + xv.y * w[1][c] + xv.z * w[2][c] + xv.w * w[3][c];
        }
    }
#pragma unroll
    for (int i = 0; i < 4; ++i) {
        float d = dinv[n0 + i];
        unsigned int p0 = pack_bf16(acc[i][0] * d, acc[i][1] * d);
        unsigned int p1 = pack_bf16(acc[i][2] * d, acc[i][3] * d);
        *(uint2*)&g1h[(size_t)(n0 + i) * 64 + (jq >> 1)] = make_uint2(p0, p1);
    }
}

// ---------------- gather layer1 + fused 128x3 GEMM2 ----------------
// one wave per node; lane holds a packed bf16 pair (elements 2*lane, 2*lane+1).
// 16 predicated loads in flight per group (invalid -> self row, zeroed).
__global__ __launch_bounds__(256) void k_gather1(const unsigned int* __restrict__ g1h,
                                                 const int* __restrict__ colsrc,
                                                 const int* __restrict__ rowptr,
                                                 const float* __restrict__ dinv,
                                                 const float* __restrict__ b1,
                                                 const float* __restrict__ W2,
                                                 float* __restrict__ g2) {
    int n = blockIdx.x * 4 + (threadIdx.x >> 6);
    int lane = threadIdx.x & 63;
    unsigned int au = g1h[(size_t)n * 64 + lane];
    float ax = __uint_as_float(au << 16);
    float ay = __uint_as_float(au & 0xffff0000u);
    int e0 = rowptr[n], eEnd = rowptr[n + 1];
    for (int e = e0; e < eEnd; e += 16) {
        unsigned int u[16];
#pragma unroll
        for (int j = 0; j < 16; ++j) {
            int idx = e + j;
            bool valid = idx < eEnd;
            int cs = colsrc[valid ? idx : e0];
            int s = valid ? cs : n;          // dummy: self row (already resident)
            u[j] = g1h[(size_t)s * 64 + lane];
            if (!valid) u[j] = 0;            // bf16 pair 0x00000000 == 0.0f,0.0f
        }
#pragma unroll
        for (int j = 0; j < 16; ++j) {
            ax += __uint_as_float(u[j] << 16);
            ay += __uint_as_float(u[j] & 0xffff0000u);
        }
    }
    float d = dinv[n];
    float2 bb = ((const float2*)b1)[lane];
    float x0 = fmaxf(ax * d + bb.x, 0.f);
    float x1 = fmaxf(ay * d + bb.y, 0.f);
    float p0 = x0 * W2[(2 * lane) * OUTC + 0] + x1 * W2[(2 * lane + 1) * OUTC + 0];
    float p1 = x0 * W2[(2 * lane) * OUTC + 1] + x1 * W2[(2 * lane + 1) * OUTC + 1];
    float p2 = x0 * W2[(2 * lane) * OUTC + 2] + x1 * W2[(2 * lane + 1) * OUTC + 2];
#pragma unroll
    for (int off = 32; off > 0; off >>= 1) {
        p0 += __shfl_down(p0, off, 64);
        p1 += __shfl_down(p1, off, 64);
        p2 += __shfl_down(p2, off, 64);
    }
    if (lane == 0) ((float4*)g2)[n] = make_float4(p0 * d, p1 * d, p2 * d, 0.f);
}

// ---------------- gather layer2: out = dinv[n]*(g2[n] + sum g2[src]) + b2 ----------------
__global__ void k_gather2(const float* __restrict__ g2, const int* __restrict__ colsrc,
                          const int* __restrict__ rowptr, const float* __restrict__ dinv,
                          const float* __restrict__ b2, float* __restrict__ out) {
    int n = blockIdx.x * blockDim.x + threadIdx.x;
    if (n >= N_NODES) return;
    const float4* gv = (const float4*)g2;
    float4 a = gv[n];
    float s0 = a.x, s1 = a.y, s2 = a.z;
    int eEnd = rowptr[n + 1];
    for (int e = rowptr[n]; e < eEnd; ++e) {
        float4 v = gv[colsrc[e]];
        s0 += v.x; s1 += v.y; s2 += v.z;
    }
    float d = dinv[n];
    out[(size_t)n * 3 + 0] = s0 * d + b2[0];
    out[(size_t)n * 3 + 1] = s1 * d + b2[1];
    out[(size_t)n * 3 + 2] = s2 * d + b2[2];
}

// ---------------- launch ----------------

extern "C" void kernel_launch(void* const* d_in, const int* in_sizes, int n_in,
                              void* d_out, int out_size, void* d_ws, size_t ws_size,
                              hipStream_t stream) {
    const float* z   = (const float*)d_in[0];
    const int*   ei  = (const int*)d_in[1];   // [2, E] int32
    const float* mat = (const float*)d_in[2];
    const float* W1  = (const float*)d_in[3];
    const float* b1  = (const float*)d_in[4];
    const float* W2  = (const float*)d_in[5];
    const float* b2  = (const float*)d_in[6];
    float* out = (float*)d_out;

    const int* srcA = ei;             // row 0 = message source
    const int* dstA = ei + N_EDGES;   // row 1 = message target

    char* ws = (char*)d_ws;
    auto alloc = [&](size_t bytes) {
        char* p = ws;
        ws += (bytes + 255) & ~(size_t)255;
        return p;
    };
    int*   gcount     = (int*)alloc(512 * 4);
    int*   bucketBase = (int*)alloc(512 * 4);
    int*   rowptr     = (int*)alloc((size_t)(N_NODES + 1) * 4);
    float* dinv       = (float*)alloc((size_t)N_NODES * 4);
    int*   colsrc     = (int*)alloc((size_t)N_EDGES * 4);
    unsigned int* g1h = (unsigned int*)alloc((size_t)N_NODES * 64 * 4);  // bf16x2 packed
    float* g2         = (float*)alloc((size_t)N_NODES * 4 * 4);
    // binned (7.2 MB) aliases g1h (25.6 MB): lifetimes are disjoint
    unsigned int* binned = g1h;

    hipMemsetAsync(gcount, 0, 512 * 4, stream);
    int nBlocksA = (N_EDGES + CHUNK - 1) / CHUNK;  // 391
    k_binA<<<nBlocksA, 256, 0, stream>>>(srcA, dstA, gcount, binned);
    k_bscan<<<1, 256, 0, stream>>>(gcount, bucketBase, rowptr);
    k_binB<<<NBKT, 256, 0, stream>>>(binned, gcount, bucketBase, colsrc, rowptr, dinv);
    k_gemm1<<<N_NODES / 32, 256, 0, stream>>>(z, mat, W1, dinv, g1h);
    k_gather1<<<N_NODES / 4, 256, 0, stream>>>(g1h, colsrc, rowptr, dinv, b1, W2, g2);
    k_gather2<<<(N_NODES + 255) / 256, 256, 0, stream>>>(g2, colsrc, rowptr, dinv, b2, out);
}

// Round 7
// 168.096 us; speedup vs baseline: 2.5551x; 1.2427x over previous
//
#include <hip/hip_runtime.h>

#define N_NODES 100000
#define N_EDGES 1600000
#define LAT 128
#define MAT 8
#define OUTC 3

#define NBKT 391          // ceil(N_NODES / 256) buckets of 256 nodes
#define CAP  4608         // per-bucket region capacity (mean 4096, sigma 64)
#define CHUNK 4096        // edges per binA block

typedef __attribute__((ext_vector_type(8))) short bf16x8;
typedef __attribute__((ext_vector_type(4))) float f32x4;

__device__ __forceinline__ unsigned short bf16r(float f) {   // RTNE fp32->bf16
    unsigned int u = __float_as_uint(f);
    u = (u + 0x7fffu + ((u >> 16) & 1u)) >> 16;
    return (unsigned short)u;
}
__device__ __forceinline__ float bf16f(unsigned short h) {
    return __uint_as_float((unsigned int)h << 16);
}
__device__ __forceinline__ unsigned int pack_bf16(float a, float b) {
    return (unsigned int)bf16r(a) | ((unsigned int)bf16r(b) << 16);
}

// ---------------- Pass A: coarse bin by dst>>8, LDS-staged for coalesced writes ----------------
__global__ __launch_bounds__(256) void k_binA(const int* __restrict__ src,
                                              const int* __restrict__ dst,
                                              int* __restrict__ gcount,
                                              unsigned int* __restrict__ binned) {
    __shared__ int hist[NBKT];
    __shared__ int adj[NBKT];            // gbase - local_exclusive_prefix
    __shared__ int cur[NBKT];            // local scatter cursor
    __shared__ int wsum[4];
    __shared__ unsigned int lbuf[CHUNK];
    __shared__ unsigned short lbkt[CHUNK];

    int t = threadIdx.x;
    int base = blockIdx.x * CHUNK;
    int nEdge = min(CHUNK, N_EDGES - base);

    for (int i = t; i < NBKT; i += 256) hist[i] = 0;
    __syncthreads();

    unsigned int pk[16];
    unsigned short bk[16];
#pragma unroll
    for (int j = 0; j < 16; ++j) {
        int li = j * 256 + t;
        if (li < nEdge) {
            int e = base + li;
            int d = dst[e];
            int s = src[e];
            pk[j] = ((unsigned int)s << 8) | (unsigned int)(d & 255);
            bk[j] = (unsigned short)(d >> 8);
            atomicAdd(&hist[bk[j]], 1);
        } else {
            bk[j] = 0xffffu;
        }
    }
    __syncthreads();

    // exclusive scan over 391 buckets: each thread owns pair (2t, 2t+1)
    int lane = t & 63, w = t >> 6;
    int i0 = 2 * t, i1 = 2 * t + 1;
    int h0 = (i0 < NBKT) ? hist[i0] : 0;
    int h1 = (i1 < NBKT) ? hist[i1] : 0;
    int ps = h0 + h1;
    int x = ps;
#pragma unroll
    for (int off = 1; off < 64; off <<= 1) {
        int y = __shfl_up(x, off, 64);
        if (lane >= off) x += y;
    }
    if (lane == 63) wsum[w] = x;
    __syncthreads();
    int woff = 0;
#pragma unroll
    for (int i = 0; i < 4; ++i)
        if (i < w) woff += wsum[i];
    int excl = woff + x - ps;   // exclusive prefix of element i0
    if (i0 < NBKT) {
        int g0 = i0 * CAP + atomicAdd(&gcount[i0], h0);
        adj[i0] = g0 - excl;
        cur[i0] = excl;
    }
    if (i1 < NBKT) {
        int g1r = i1 * CAP + atomicAdd(&gcount[i1], h1);
        adj[i1] = g1r - (excl + h0);
        cur[i1] = excl + h0;
    }
    __syncthreads();

    // local scatter into bucket-sorted LDS order
#pragma unroll
    for (int j = 0; j < 16; ++j) {
        if (bk[j] != 0xffffu) {
            int pos = atomicAdd(&cur[bk[j]], 1);
            lbuf[pos] = pk[j];
            lbkt[pos] = bk[j];
        }
    }
    __syncthreads();

    // linear, coalesced write-out: contiguous within-bucket chunks
    for (int i = t; i < nEdge; i += 256) {
        int b = lbkt[i];
        binned[adj[b] + i] = lbuf[i];
    }
}

// ---------------- scan of 391 bucket counts -> bucketBase ----------------
__global__ __launch_bounds__(256) void k_bscan(const int* __restrict__ gcount,
                                               int* __restrict__ bucketBase,
                                               int* __restrict__ rowptr) {
    __shared__ int wsum[4];
    int t = threadIdx.x;
    int lane = t & 63, w = t >> 6;
    int i0 = 2 * t, i1 = 2 * t + 1;
    int h0 = (i0 < NBKT) ? gcount[i0] : 0;
    int h1 = (i1 < NBKT) ? gcount[i1] : 0;
    int ps = h0 + h1;
    int x = ps;
#pragma unroll
    for (int off = 1; off < 64; off <<= 1) {
        int y = __shfl_up(x, off, 64);
        if (lane >= off) x += y;
    }
    if (lane == 63) wsum[w] = x;
    __syncthreads();
    int woff = 0;
#pragma unroll
    for (int i = 0; i < 4; ++i)
        if (i < w) woff += wsum[i];
    int excl = woff + x - ps;
    bucketBase[i0] = excl;
    bucketBase[i1] = excl + h0;
    if (t == 0) rowptr[N_NODES] = N_EDGES;
}

// ---------------- Pass B: fine sort within bucket, emit colsrc + rowptr + dinv ----------------
__global__ __launch_bounds__(256) void k_binB(const unsigned int* __restrict__ binned,
                                              const int* __restrict__ gcount,
                                              const int* __restrict__ bucketBase,
                                              int* __restrict__ colsrc,
                                              int* __restrict__ rowptr,
                                              float* __restrict__ dinv) {
    __shared__ unsigned int lbuf[CAP];
    __shared__ int lsrc[CAP];
    __shared__ int hist[256];
    __shared__ int cur[256];
    __shared__ int wsum[4];

    int b = blockIdx.x, t = threadIdx.x;
    int cnt = min(gcount[b], CAP);
    int gb = bucketBase[b];
    const unsigned int* bp = binned + (size_t)b * CAP;

    for (int i = t; i < cnt; i += 256) lbuf[i] = bp[i];
    hist[t] = 0;
    __syncthreads();
    for (int i = t; i < cnt; i += 256) atomicAdd(&hist[lbuf[i] & 255], 1);
    __syncthreads();

    // exclusive scan of hist[256]
    int lane = t & 63, w = t >> 6;
    int h = hist[t];
    int x = h;
#pragma unroll
    for (int off = 1; off < 64; off <<= 1) {
        int y = __shfl_up(x, off, 64);
        if (lane >= off) x += y;
    }
    if (lane == 63) wsum[w] = x;
    __syncthreads();
    int woff = 0;
#pragma unroll
    for (int i = 0; i < 4; ++i)
        if (i < w) woff += wsum[i];
    int excl = woff + x - h;
    cur[t] = excl;

    int node = b * 256 + t;
    if (node < N_NODES) {
        rowptr[node] = gb + excl;
        dinv[node] = rsqrtf((float)h + 1.0f);   // +1 self-loop
    }
    __syncthreads();

    for (int i = t; i < cnt; i += 256) {
        unsigned int p = lbuf[i];
        int pos = atomicAdd(&cur[p & 255], 1);
        lsrc[pos] = (int)(p >> 8);
    }
    __syncthreads();

    for (int i = t; i < cnt; i += 256) colsrc[gb + i] = lsrc[i];
}

// ---------------- W1 split: fp32 [136][128] -> bf16 hi/lo [160][128], zero-padded ----------------
__global__ void k_wsplit(const float* __restrict__ W1,
                         unsigned short* __restrict__ w1h,
                         unsigned short* __restrict__ w1l) {
    int i = blockIdx.x * 256 + threadIdx.x;
    if (i >= 160 * 128) return;
    int k = i >> 7;
    float w = (k < LAT + MAT) ? W1[i] : 0.f;
    unsigned short h = bf16r(w);
    w1h[i] = h;
    w1l[i] = bf16r(w - bf16f(h));
}

// ---------------- GEMM1 via split-bf16 MFMA ----------------
// g1 = (concat(z,mat) @ W1) * dinv,  x ~= xh + xl (bf16 each), W ~= Wh + Wl.
// x@W ~= xh@Wh + xl@Wh + xh@Wl  (xl@Wl ~ 2^-16 rel, dropped).
// block = 4 waves; wave w owns cols [32w, 32w+32) as 2 MFMA col-tiles; B-frags
// live in VGPRs for the whole kernel; grid-stride over 16-node tiles. No LDS.
__global__ __launch_bounds__(256) void k_gemm1m(const float* __restrict__ z,
                                                const float* __restrict__ mat,
                                                const unsigned short* __restrict__ w1h,
                                                const unsigned short* __restrict__ w1l,
                                                const float* __restrict__ dinv,
                                                unsigned short* __restrict__ g1h) {
    int wv = threadIdx.x >> 6;
    int l = threadIdx.x & 63;
    int lm = l & 15, q = l >> 4;

    // B fragments: B[k][col], lane -> col = base+lm, k = ks*32 + q*8 + j
    bf16x8 bh[2][5], bl[2][5];
#pragma unroll
    for (int ct = 0; ct < 2; ++ct) {
        int col = (wv * 2 + ct) * 16 + lm;
#pragma unroll
        for (int ks = 0; ks < 5; ++ks) {
#pragma unroll
            for (int j = 0; j < 8; ++j) {
                int k = ks * 32 + q * 8 + j;
                bh[ct][ks][j] = (short)w1h[k * 128 + col];
                bl[ct][ks][j] = (short)w1l[k * 128 + col];
            }
        }
    }

    for (int tile = blockIdx.x; tile < N_NODES / 16; tile += gridDim.x) {
        int n0 = tile * 16;
        int row = n0 + lm;                     // A row for this lane
        f32x4 acc0 = {0.f, 0.f, 0.f, 0.f};
        f32x4 acc1 = {0.f, 0.f, 0.f, 0.f};
#pragma unroll
        for (int ks = 0; ks < 5; ++ks) {
            float a[8];
            if (ks < 4) {
                float4 a0 = *(const float4*)&z[(size_t)row * LAT + ks * 32 + q * 8];
                float4 a1 = *(const float4*)&z[(size_t)row * LAT + ks * 32 + q * 8 + 4];
                a[0] = a0.x; a[1] = a0.y; a[2] = a0.z; a[3] = a0.w;
                a[4] = a1.x; a[5] = a1.y; a[6] = a1.z; a[7] = a1.w;
            } else if (q == 0) {               // k = 128..135 -> mat[0..7]
                float4 m0 = *(const float4*)&mat[(size_t)row * MAT];
                float4 m1 = *(const float4*)&mat[(size_t)row * MAT + 4];
                a[0] = m0.x; a[1] = m0.y; a[2] = m0.z; a[3] = m0.w;
                a[4] = m1.x; a[5] = m1.y; a[6] = m1.z; a[7] = m1.w;
            } else {                           // k = 136..159 -> zero pad
#pragma unroll
                for (int j = 0; j < 8; ++j) a[j] = 0.f;
            }
            bf16x8 ah, al;
#pragma unroll
            for (int j = 0; j < 8; ++j) {
                unsigned short h = bf16r(a[j]);
                ah[j] = (short)h;
                al[j] = (short)bf16r(a[j] - bf16f(h));
            }
            acc0 = __builtin_amdgcn_mfma_f32_16x16x32_bf16(ah, bh[0][ks], acc0, 0, 0, 0);
            acc1 = __builtin_amdgcn_mfma_f32_16x16x32_bf16(ah, bh[1][ks], acc1, 0, 0, 0);
            acc0 = __builtin_amdgcn_mfma_f32_16x16x32_bf16(al, bh[0][ks], acc0, 0, 0, 0);
            acc1 = __builtin_amdgcn_mfma_f32_16x16x32_bf16(al, bh[1][ks], acc1, 0, 0, 0);
            acc0 = __builtin_amdgcn_mfma_f32_16x16x32_bf16(ah, bl[0][ks], acc0, 0, 0, 0);
            acc1 = __builtin_amdgcn_mfma_f32_16x16x32_bf16(ah, bl[1][ks], acc1, 0, 0, 0);
        }
        // D layout: col = lm, row = q*4 + r
#pragma unroll
        for (int r = 0; r < 4; ++r) {
            int m = q * 4 + r;
            float d = dinv[n0 + m];
            g1h[(size_t)(n0 + m) * 128 + (wv * 2 + 0) * 16 + lm] = bf16r(acc0[r] * d);
            g1h[(size_t)(n0 + m) * 128 + (wv * 2 + 1) * 16 + lm] = bf16r(acc1[r] * d);
        }
    }
}

// ---------------- gather layer1 + fused 128x3 GEMM2 ----------------
// one wave per node; lane holds a packed bf16 pair (elements 2*lane, 2*lane+1).
// 16 predicated loads in flight per group (invalid -> self row, zeroed).
__global__ __launch_bounds__(256) void k_gather1(const unsigned int* __restrict__ g1h,
                                                 const int* __restrict__ colsrc,
                                                 const int* __restrict__ rowptr,
                                                 const float* __restrict__ dinv,
                                                 const float* __restrict__ b1,
                                                 const float* __restrict__ W2,
                                                 float* __restrict__ g2) {
    int n = blockIdx.x * 4 + (threadIdx.x >> 6);
    int lane = threadIdx.x & 63;
    unsigned int au = g1h[(size_t)n * 64 + lane];
    float ax = __uint_as_float(au << 16);
    float ay = __uint_as_float(au & 0xffff0000u);
    int e0 = rowptr[n], eEnd = rowptr[n + 1];
    for (int e = e0; e < eEnd; e += 16) {
        unsigned int u[16];
#pragma unroll
        for (int j = 0; j < 16; ++j) {
            int idx = e + j;
            bool valid = idx < eEnd;
            int cs = colsrc[valid ? idx : e0];
            int s = valid ? cs : n;          // dummy: self row (already resident)
            u[j] = g1h[(size_t)s * 64 + lane];
            if (!valid) u[j] = 0;            // bf16 pair 0x00000000 == 0.0f,0.0f
        }
#pragma unroll
        for (int j = 0; j < 16; ++j) {
            ax += __uint_as_float(u[j] << 16);
            ay += __uint_as_float(u[j] & 0xffff0000u);
        }
    }
    float d = dinv[n];
    float2 bb = ((const float2*)b1)[lane];
    float x0 = fmaxf(ax * d + bb.x, 0.f);
    float x1 = fmaxf(ay * d + bb.y, 0.f);
    float p0 = x0 * W2[(2 * lane) * OUTC + 0] + x1 * W2[(2 * lane + 1) * OUTC + 0];
    float p1 = x0 * W2[(2 * lane) * OUTC + 1] + x1 * W2[(2 * lane + 1) * OUTC + 1];
    float p2 = x0 * W2[(2 * lane) * OUTC + 2] + x1 * W2[(2 * lane + 1) * OUTC + 2];
#pragma unroll
    for (int off = 32; off > 0; off >>= 1) {
        p0 += __shfl_down(p0, off, 64);
        p1 += __shfl_down(p1, off, 64);
        p2 += __shfl_down(p2, off, 64);
    }
    if (lane == 0) ((float4*)g2)[n] = make_float4(p0 * d, p1 * d, p2 * d, 0.f);
}

// ---------------- gather layer2: out = dinv[n]*(g2[n] + sum g2[src]) + b2 ----------------
__global__ void k_gather2(const float* __restrict__ g2, const int* __restrict__ colsrc,
                          const int* __restrict__ rowptr, const float* __restrict__ dinv,
                          const float* __restrict__ b2, float* __restrict__ out) {
    int n = blockIdx.x * blockDim.x + threadIdx.x;
    if (n >= N_NODES) return;
    const float4* gv = (const float4*)g2;
    float4 a = gv[n];
    float s0 = a.x, s1 = a.y, s2 = a.z;
    int eEnd = rowptr[n + 1];
    for (int e = rowptr[n]; e < eEnd; ++e) {
        float4 v = gv[colsrc[e]];
        s0 += v.x; s1 += v.y; s2 += v.z;
    }
    float d = dinv[n];
    out[(size_t)n * 3 + 0] = s0 * d + b2[0];
    out[(size_t)n * 3 + 1] = s1 * d + b2[1];
    out[(size_t)n * 3 + 2] = s2 * d + b2[2];
}

// ---------------- launch ----------------

extern "C" void kernel_launch(void* const* d_in, const int* in_sizes, int n_in,
                              void* d_out, int out_size, void* d_ws, size_t ws_size,
                              hipStream_t stream) {
    const float* z   = (const float*)d_in[0];
    const int*   ei  = (const int*)d_in[1];   // [2, E] int32
    const float* mat = (const float*)d_in[2];
    const float* W1  = (const float*)d_in[3];
    const float* b1  = (const float*)d_in[4];
    const float* W2  = (const float*)d_in[5];
    const float* b2  = (const float*)d_in[6];
    float* out = (float*)d_out;

    const int* srcA = ei;             // row 0 = message source
    const int* dstA = ei + N_EDGES;   // row 1 = message target

    char* ws = (char*)d_ws;
    auto alloc = [&](size_t bytes) {
        char* p = ws;
        ws += (bytes + 255) & ~(size_t)255;
        return p;
    };
    int*   gcount     = (int*)alloc(512 * 4);
    int*   bucketBase = (int*)alloc(512 * 4);
    int*   rowptr     = (int*)alloc((size_t)(N_NODES + 1) * 4);
    float* dinv       = (float*)alloc((size_t)N_NODES * 4);
    int*   colsrc     = (int*)alloc((size_t)N_EDGES * 4);
    unsigned int* g1h = (unsigned int*)alloc((size_t)N_NODES * 64 * 4);  // bf16x2 packed
    float* g2         = (float*)alloc((size_t)N_NODES * 4 * 4);
    unsigned short* w1h = (unsigned short*)alloc(160 * 128 * 2);
    unsigned short* w1l = (unsigned short*)alloc(160 * 128 * 2);
    // binned (7.2 MB) aliases g1h (25.6 MB): lifetimes are disjoint
    unsigned int* binned = g1h;

    hipMemsetAsync(gcount, 0, 512 * 4, stream);
    int nBlocksA = (N_EDGES + CHUNK - 1) / CHUNK;  // 391
    k_binA<<<nBlocksA, 256, 0, stream>>>(srcA, dstA, gcount, binned);
    k_bscan<<<1, 256, 0, stream>>>(gcount, bucketBase, rowptr);
    k_binB<<<NBKT, 256, 0, stream>>>(binned, gcount, bucketBase, colsrc, rowptr, dinv);
    k_wsplit<<<(160 * 128 + 255) / 256, 256, 0, stream>>>(W1, w1h, w1l);
    k_gemm1m<<<1250, 256, 0, stream>>>(z, mat, w1h, w1l, dinv, (unsigned short*)g1h);
    k_gather1<<<N_NODES / 4, 256, 0, stream>>>(g1h, colsrc, rowptr, dinv, b1, W2, g2);
    k_gather2<<<(N_NODES + 255) / 256, 256, 0, stream>>>(g2, colsrc, rowptr, dinv, b2, out);
}